// Round 4
// baseline (1990.200 us; speedup 1.0000x reference)
//
#include <hip/hip_runtime.h>

#define R_ 16
#define T_ 512
#define N_ 256
#define DTOT 1278  // 2*(T-1) + (N-1) + 1 diagonals; divisible by 3

constexpr float TWO_LOG2E = 2.8853900817779268f;  // 2*log2(e)
constexpr float LOG2E     = 1.4426950408889634f;

// ---------------------------------------------------------------------------
// Kernel 1: pre[r,t,i,j] = (b1[j] + sum_k x[r,t,i,k]*W1[k,j]) * 2log2e
// float4-coalesced LDS staging; W1,b1 pre-scaled in LDS (broadcast reads).
// Safe in-place (pre==runs): full tile staged before any global write.
// ---------------------------------------------------------------------------
__global__ __launch_bounds__(256) void pre_kernel(const float* __restrict__ runs,
                                                  const float* __restrict__ W1,
                                                  const float* __restrict__ b1,
                                                  float* __restrict__ pre) {
    __shared__ float4 sx4[1408];          // 5632 floats = 256 rows x 22
    __shared__ float sw[506];             // W1 (484) + b1 (22), pre-scaled
    float* sx = (float*)sx4;

    for (int m = threadIdx.x; m < 506; m += 256)
        sw[m] = (m < 484 ? W1[m] : b1[m - 484]) * TWO_LOG2E;

    const float4* rin = (const float4*)(runs + (size_t)blockIdx.x * 5632);
    for (int m = threadIdx.x; m < 1408; m += 256) sx4[m] = rin[m];
    __syncthreads();

    float x[22];
    const float2* rowp = (const float2*)(sx + threadIdx.x * 22);
#pragma unroll
    for (int p = 0; p < 11; ++p) { float2 w = rowp[p]; x[2*p] = w.x; x[2*p+1] = w.y; }

    float acc[22];
#pragma unroll
    for (int j = 0; j < 22; ++j) acc[j] = sw[484 + j];
#pragma unroll
    for (int k = 0; k < 22; ++k) {
        float xk = x[k];
        const float* wr = &sw[k * 22];
#pragma unroll
        for (int j = 0; j < 22; ++j) acc[j] = fmaf(xk, wr[j], acc[j]);
    }
    __syncthreads();  // everyone done reading sx before overwrite
    float2* roww = (float2*)(sx + threadIdx.x * 22);
#pragma unroll
    for (int p = 0; p < 11; ++p) roww[p] = make_float2(acc[2*p], acc[2*p+1]);
    __syncthreads();

    float4* pout = (float4*)(pre + (size_t)blockIdx.x * 5632);
    for (int m = threadIdx.x; m < 1408; m += 256) pout[m] = sx4[m];
}

// ---------------------------------------------------------------------------
// Kernel 2: diagonal-wavefront recurrence, TWO runs per block.
// Step (t,i) on diagonal d=2t+i; deps on d-1; same-parity i within a diagonal
// means writes (i+1) never collide with reads (i,i+2) -> one barrier/diagonal.
// Block: 512 thr = run A (tid<256) + run B. Per run: 128 steps x 2 lanes.
// Lane l of a step handles 12 hidden units j = 12l..12l+11 (j<22; tail zeroed).
// Run B's waves fill run A's latency stalls on the shared SIMDs.
// ---------------------------------------------------------------------------
__device__ __forceinline__ float dpp_xor1(float x) {
    int i = __builtin_bit_cast(int, x);
    i = __builtin_amdgcn_update_dpp(0, i, 0xB1, 0xF, 0xF, true);  // quad_perm [1,0,3,2]
    return __builtin_bit_cast(float, i);
}

__global__ __launch_bounds__(512, 1) void wave_kernel(const float* __restrict__ pre,
                                                      const float* __restrict__ comm0,
                                                      const float* __restrict__ W1,
                                                      const float* __restrict__ W2,
                                                      const float* __restrict__ b2,
                                                      float* __restrict__ out) {
    __shared__ float comm[2][N_ + 2];
    const int tid = threadIdx.x;
    const int rsel = tid >> 8;           // which run-half of the block
    const int ltid = tid & 255;
    const int r = 2 * blockIdx.x + rsel;
    const int sidx = ltid >> 1;          // step index in diagonal (0..127)
    const int l = ltid & 1;              // lane within step
    const int jb = l * 12;

    for (int m = tid; m < 2 * (N_ + 2); m += 512) {
        int q = m / (N_ + 2), p = m - q * (N_ + 2);
        comm[q][p] = (p == 0 || p == N_ + 1)
                         ? 0.f
                         : comm0[(2 * blockIdx.x + q) * (N_ + 2) + p];
    }

    // per-lane weight slices (zero-padded past j=21)
    float A2[12], B2[12], Wa[12], Wb[12];
#pragma unroll
    for (int q = 0; q < 12; ++q) {
        int j = jb + q;
        bool jv = (j < 22);
        A2[q] = jv ? W1[484 + j] * TWO_LOG2E : 0.f;  // W1[22][j] (left)
        B2[q] = jv ? W1[506 + j] * TWO_LOG2E : 0.f;  // W1[23][j] (right)
        Wa[q] = jv ? W2[2 * j] : 0.f;
        Wb[q] = jv ? W2[2 * j + 1] : 0.f;
    }
    const float bb0 = b2[0], bb1 = b2[1];
    const float* preR = pre + (size_t)r * ((size_t)T_ * N_ * 22);
    float* outR = out + (size_t)r * ((size_t)T_ * N_);
    float* commS = comm[rsel];
    __syncthreads();  // covers comm init

    const int f2b = l * 6;  // first float2 index of this lane's j-block

    float pA[12], pB[12], pC[12], h[12];

    auto PF = [&](float* buf, int d) {
        int tl = (d > 255) ? ((d - 254) >> 1) : 0;
        int t = tl + sidx;
        int i = d - 2 * t;
        bool v = (t < T_) && (i >= 0);
        size_t row = v ? ((size_t)t * N_ + i) : 0;  // invalid -> row 0 (unused)
        const float2* p = reinterpret_cast<const float2*>(preR + row * 22);
#pragma unroll
        for (int q = 0; q < 6; ++q) {
            int fi = f2b + q; if (fi > 10) fi = 10;  // lane1 tail dup (weights 0)
            float2 w = p[fi];
            buf[2 * q] = w.x; buf[2 * q + 1] = w.y;
        }
    };

    // ST1: everything needed for the comm update (the true critical path)
    auto ST1 = [&](int d, float* buf) {
        int tl = (d > 255) ? ((d - 254) >> 1) : 0;
        int t = tl + sidx;
        int i = d - 2 * t;
        bool v = (t < T_) && (i >= 0);
        int iu = i < 0 ? 0 : (i > 255 ? 255 : i);   // clamped unconditional read
        float left = commS[iu], right = commS[iu + 2];
        float a1 = 0.f;
#pragma unroll
        for (int q = 0; q < 12; ++q) {
            float u = fmaf(right, B2[q], fmaf(left, A2[q], buf[q]));
            float e = __builtin_amdgcn_exp2f(u);                        // e^(2z)
            h[q] = fmaf(-2.f, __builtin_amdgcn_rcpf(1.f + e), 1.f);     // tanh(z)
            a1 = fmaf(h[q], Wb[q], a1);
        }
        a1 += dpp_xor1(a1);
        if (v && l == 0) {
            float o1 = a1 + bb1;
            commS[i + 1] = __builtin_amdgcn_rcpf(
                1.f + __builtin_amdgcn_exp2f(-LOG2E * o1));             // sigmoid
        }
    };

    // ST2: control output — off the critical path, issued after the barrier
    auto ST2 = [&](int d) {
        int tl = (d > 255) ? ((d - 254) >> 1) : 0;
        int t = tl + sidx;
        int i = d - 2 * t;
        bool v = (t < T_) && (i >= 0);
        float a0 = 0.f;
#pragma unroll
        for (int q = 0; q < 12; ++q) a0 = fmaf(h[q], Wa[q], a0);
        a0 += dpp_xor1(a0);
        if (v && l == 0) outR[(size_t)t * N_ + i] = a0 + bb0;
    };

    // lgkmcnt(0) drains our LDS ops pre-barrier; trailing empty asm is a
    // compiler fence (raw s_barrier is not an LLVM memory fence). No vmcnt
    // drain: prefetch loads stay in flight across barriers.
#define BAR() do { asm volatile("s_waitcnt lgkmcnt(0)" ::: "memory"); \
                   __builtin_amdgcn_s_barrier();                      \
                   asm volatile("" ::: "memory"); } while (0)

    PF(pA, 0);
    PF(pB, 1);
    for (int d = 0; d < DTOT; d += 3) {
        PF(pC, d + 2); ST1(d, pA);     BAR(); ST2(d);
        PF(pA, d + 3); ST1(d + 1, pB); BAR(); ST2(d + 1);
        PF(pB, d + 4); ST1(d + 2, pC); BAR(); ST2(d + 2);
    }
#undef BAR
}

// ---------------------------------------------------------------------------
extern "C" void kernel_launch(void* const* d_in, const int* in_sizes, int n_in,
                              void* d_out, int out_size, void* d_ws, size_t ws_size,
                              hipStream_t stream) {
    const float* runs  = (const float*)d_in[0];
    const float* comm0 = (const float*)d_in[1];
    const float* W1    = (const float*)d_in[2];
    const float* b1    = (const float*)d_in[3];
    const float* W2    = (const float*)d_in[4];
    const float* b2    = (const float*)d_in[5];
    float* out = (float*)d_out;

    const size_t preBytes = (size_t)R_ * T_ * N_ * 22 * sizeof(float);
    // Prefer workspace; fall back to in-place overwrite of runs (harness
    // restores d_in before every launch; pre_kernel stages the whole tile
    // through LDS so in-place is race-free).
    float* pre = (ws_size >= preBytes) ? (float*)d_ws : (float*)d_in[0];

    pre_kernel<<<(R_ * T_ * N_) / 256, 256, 0, stream>>>(runs, W1, b1, pre);
    wave_kernel<<<R_ / 2, 512, 0, stream>>>(pre, comm0, W1, W2, b2, out);
}

// Round 15
// 1351.842 us; speedup vs baseline: 1.4722x; 1.4722x over previous
//
#include <hip/hip_runtime.h>

#define R_ 16
#define T_ 512
#define N_ 256

constexpr float TWO_LOG2E = 2.8853900817779268f;  // 2*log2(e)
constexpr float LOG2E     = 1.4426950408889634f;

// ---------------------------------------------------------------------------
// Kernel 1: pre[r,t,i,j] = (b1[j] + sum_k x[r,t,i,k]*W1[k,j]) * 2log2e
// float4-coalesced LDS staging; W1,b1 pre-scaled in LDS (broadcast reads).
// Safe in-place (pre==runs): full tile staged before any global write.
// ---------------------------------------------------------------------------
__global__ __launch_bounds__(256) void pre_kernel(const float* __restrict__ runs,
                                                  const float* __restrict__ W1,
                                                  const float* __restrict__ b1,
                                                  float* __restrict__ pre) {
    __shared__ float4 sx4[1408];          // 5632 floats = 256 rows x 22
    __shared__ float sw[506];             // W1 (484) + b1 (22), pre-scaled
    float* sx = (float*)sx4;

    for (int m = threadIdx.x; m < 506; m += 256)
        sw[m] = (m < 484 ? W1[m] : b1[m - 484]) * TWO_LOG2E;

    const float4* rin = (const float4*)(runs + (size_t)blockIdx.x * 5632);
    for (int m = threadIdx.x; m < 1408; m += 256) sx4[m] = rin[m];
    __syncthreads();

    float x[22];
    const float2* rowp = (const float2*)(sx + threadIdx.x * 22);
#pragma unroll
    for (int p = 0; p < 11; ++p) { float2 w = rowp[p]; x[2*p] = w.x; x[2*p+1] = w.y; }

    float acc[22];
#pragma unroll
    for (int j = 0; j < 22; ++j) acc[j] = sw[484 + j];
#pragma unroll
    for (int k = 0; k < 22; ++k) {
        float xk = x[k];
        const float* wr = &sw[k * 22];
#pragma unroll
        for (int j = 0; j < 22; ++j) acc[j] = fmaf(xk, wr[j], acc[j]);
    }
    __syncthreads();  // everyone done reading sx before overwrite
    float2* roww = (float2*)(sx + threadIdx.x * 22);
#pragma unroll
    for (int p = 0; p < 11; ++p) roww[p] = make_float2(acc[2*p], acc[2*p+1]);
    __syncthreads();

    float4* pout = (float4*)(pre + (size_t)blockIdx.x * 5632);
    for (int m = threadIdx.x; m < 1408; m += 256) pout[m] = sx4[m];
}

// ---------------------------------------------------------------------------
// Kernel 2: register-resident wavefront. ONE WAVE per run, no LDS, no barriers.
// Lane k owns agents 4k..4k+3; at super-step s it runs timestep t = s-k
// (lane k-1 is one timestep AHEAD of lane k).
// comm state per lane: pw0..pw3 = comm[4k+1..4k+4] after this lane's last
// timestep (init = comm0). Cross-lane traffic: 2 shuffles per super-step.
//   agent 4k  : left = Lin = shfl_up(lane k-1 pw3 @ end of s-1)
//               [= comm[4k] written at timestep t by agent 4k-1]
//               right = pw1 (own, t-1)
//   agent 4k+1: left = nw0 (own, t), right = pw2 (own, t-1)
//   agent 4k+2: left = nw1,          right = pw3 (own, t-1)
//   agent 4k+3: left = nw2, right = Rin = shfl_down(lane k+1 nw0 this s | pw0)
//               [= comm[4k+5] written at timestep t-1 by agent 4k+4]
// tanh folded: h = 1 - 2*rcp(1+exp2(u)); W2-reduce uses Wa' = -2*Wa and
// uniform sums so per hidden unit: 2 fma + exp2 + rcp + 2 fma.
// fmaf nesting puts (right*B2 + pre) INNER so it is independent of the
// serially-produced `left` -> hoistable off the nw-chain (ILP).
// ---------------------------------------------------------------------------
__global__ __launch_bounds__(64, 1) void wave_kernel(const float* __restrict__ pre,
                                                     const float* __restrict__ comm0,
                                                     const float* __restrict__ W1,
                                                     const float* __restrict__ W2,
                                                     const float* __restrict__ b2,
                                                     float* __restrict__ out) {
    const int k = threadIdx.x;           // 0..63
    const int r = blockIdx.x;
    const float* preR = pre + (size_t)r * ((size_t)T_ * N_ * 22);
    float* outR = out + (size_t)r * ((size_t)T_ * N_);

    float A2[22], B2[22], Wa2[22], Wb2[22];
    float sWa = b2[0], sWb = b2[1];
#pragma unroll
    for (int j = 0; j < 22; ++j) {
        A2[j] = W1[484 + j] * TWO_LOG2E;     // W1[22][j] (left),  pre-scaled
        B2[j] = W1[506 + j] * TWO_LOG2E;     // W1[23][j] (right), pre-scaled
        float wa = W2[2 * j], wb = W2[2 * j + 1];
        sWa += wa; sWb += wb;                // h==1 baseline contribution
        Wa2[j] = -2.f * wa; Wb2[j] = -2.f * wb;
    }

    float pw0 = comm0[r * (N_ + 2) + 4 * k + 1];
    float pw1 = comm0[r * (N_ + 2) + 4 * k + 2];
    float pw2 = comm0[r * (N_ + 2) + 4 * k + 3];
    float pw3 = comm0[r * (N_ + 2) + 4 * k + 4];

    float cA[88], cB[88];  // double-buffered pre rows (static indices only)

    auto PF = [&](float (&buf)[88], int s) {
        int t = s - k;
        bool v = (t >= 0) && (t < T_);
        size_t row = v ? ((size_t)t * N_ + 4 * k) : 0;  // clamp: finite, unused
        const float4* src = reinterpret_cast<const float4*>(preR + row * 22);
#pragma unroll
        for (int m = 0; m < 22; ++m) {
            float4 w = src[m];
            buf[4 * m] = w.x; buf[4 * m + 1] = w.y;
            buf[4 * m + 2] = w.z; buf[4 * m + 3] = w.w;
        }
    };

    auto AGENT = [&](const float (&pb)[88], int c, float left, float right,
                     float& ctrl) {
        float s0a = 0.f, s0b = 0.f;                      // ctrl: 2-way (off-path)
        float s1a = 0.f, s1b = 0.f, s1c = 0.f, s1d = 0.f; // o1: 4-way (critical)
#pragma unroll
        for (int j = 0; j < 22; ++j) {
            // inner term independent of `left` -> computable before nw arrives
            float u = fmaf(left, A2[j], fmaf(right, B2[j], pb[c * 22 + j]));
            float rj = __builtin_amdgcn_rcpf(1.f + __builtin_amdgcn_exp2f(u));
            if (j & 1) s0b = fmaf(rj, Wa2[j], s0b);
            else       s0a = fmaf(rj, Wa2[j], s0a);
            switch (j & 3) {
                case 0: s1a = fmaf(rj, Wb2[j], s1a); break;
                case 1: s1b = fmaf(rj, Wb2[j], s1b); break;
                case 2: s1c = fmaf(rj, Wb2[j], s1c); break;
                default: s1d = fmaf(rj, Wb2[j], s1d); break;
            }
        }
        ctrl = sWa + s0a + s0b;
        float o1 = sWb + ((s1a + s1b) + (s1c + s1d));
        return __builtin_amdgcn_rcpf(1.f + __builtin_amdgcn_exp2f(-LOG2E * o1));
    };

    float Lin = 0.f;  // s=0: only lane 0 active and comm[0]=0 -> correct

    auto BODY = [&](const float (&pb)[88], int s) {
        int t = s - k;
        bool act = (t >= 0) && (t < T_);
        float c0, c1, c2, c3;
        float nw0 = AGENT(pb, 0, Lin, pw1, c0);
        // comm[4k+5] @ t-1: lane k+1's nw0 if started, else its init pw0
        float send = act ? nw0 : pw0;
        float Rin = __shfl_down(send, 1);
        if (k == 63) Rin = 0.f;              // comm[257] sentinel
        float nw1 = AGENT(pb, 1, nw0, pw2, c1);
        float nw2 = AGENT(pb, 2, nw1, pw3, c2);
        float nw3 = AGENT(pb, 3, nw2, Rin, c3);
        if (act) {
            pw0 = nw0; pw1 = nw1; pw2 = nw2; pw3 = nw3;
            *reinterpret_cast<float4*>(outR + (size_t)t * N_ + 4 * k) =
                make_float4(c0, c1, c2, c3);
        }
        float Ls = __shfl_up(pw3, 1);        // comm[4k] for next super-step
        Lin = (k == 0) ? 0.f : Ls;           // comm[0] sentinel
    };

    // super-steps s = 0..574 active; 575 is a harmless dead pass (even trip)
    PF(cA, 0);
    for (int s = 0; s < 576; s += 2) {
        PF(cB, s + 1);   // prefetch next while computing current
        BODY(cA, s);
        PF(cA, s + 2);
        BODY(cB, s + 1);
    }
}

// ---------------------------------------------------------------------------
extern "C" void kernel_launch(void* const* d_in, const int* in_sizes, int n_in,
                              void* d_out, int out_size, void* d_ws, size_t ws_size,
                              hipStream_t stream) {
    const float* runs  = (const float*)d_in[0];
    const float* comm0 = (const float*)d_in[1];
    const float* W1    = (const float*)d_in[2];
    const float* b1    = (const float*)d_in[3];
    const float* W2    = (const float*)d_in[4];
    const float* b2    = (const float*)d_in[5];
    float* out = (float*)d_out;

    const size_t preBytes = (size_t)R_ * T_ * N_ * 22 * sizeof(float);
    // Prefer workspace; fall back to in-place overwrite of runs (harness
    // restores d_in before every launch; pre_kernel stages the whole tile
    // through LDS so in-place is race-free).
    float* pre = (ws_size >= preBytes) ? (float*)d_ws : (float*)d_in[0];

    pre_kernel<<<(R_ * T_ * N_) / 256, 256, 0, stream>>>(runs, W1, b1, pre);
    wave_kernel<<<R_, 64, 0, stream>>>(pre, comm0, W1, W2, b2, out);
}